// Round 6
// baseline (342.534 us; speedup 1.0000x reference)
//
#include <hip/hip_runtime.h>

// CTC forward loss (sum, zero_infinity), B=32, T=1024, V=1024, L=256, S=513.
//
// Pass 1 (ctc_gather): per (b,t) row, gather the 257 needed probs, exp(),
//   write labels compacted in-place (cols 0..255); blank prob stored SHIFTED
//   (blank of step t at blanks[b*T + t-1]; blank of t=0 at slot T-1) so the
//   DP can read blanks as 16B-aligned float4s.
//
// Pass 2 (ctc_dp): one block (2 waves) per batch item — PRODUCER/CONSUMER
//   wave specialization. Producer (wave 1) stages 16-step chunks of label
//   probs into a 4-deep LDS ring with global_load_lds(16B) and publishes
//   with an LDS release-atomic after s_waitcnt vmcnt. Consumer (wave 0)
//   runs the linear-domain DP reading ONLY LDS — its loop has zero VM ops,
//   so its waitcnts are precise lgkmcnt (per-wave counters: the producer's
//   vmcnt stalls don't touch it). This sidesteps all three single-wave
//   prefetch failures seen in R3 (loads sunk to uses), R4 (conservative
//   vmcnt(0) before ds_read), R5 (buffer spill to scratch).
//   States in registers (lane l: 8l..8l+7; lane 63 also 512); exact pow-2
//   rescale every 8 steps; epilogue via shuffles only.

constexpr int B_ = 32, T_ = 1024, V_ = 1024, L_ = 256;
constexpr int S_ = 2 * L_ + 1;   // 513
constexpr int CH = 16;           // steps per chunk
constexpr int NCHUNK = 64;       // 64*16 covers t = 1..1024 (guarded/clamped)
constexpr int NBUF = 4;          // LDS ring depth (64 KB)
constexpr float LN2F = 0.6931471805599453f;

typedef const __attribute__((address_space(1))) unsigned int* gp_t;
typedef __attribute__((address_space(3))) unsigned int* lp_t;

__global__ __launch_bounds__(256, 4) void ctc_gather(
    float* __restrict__ lp, const int* __restrict__ labels,
    float* __restrict__ blanks)
{
    const int wave = threadIdx.x >> 6;
    const int lane = threadIdx.x & 63;
    const int r = blockIdx.x * 4 + wave;       // row in [0, B*T)
    const int b = r >> 10;                     // T = 1024
    float* row = lp + (size_t)r * V_;
    const int* labb = labels + b * L_;

    const int4 e = *(const int4*)(labb + 4 * lane);
    const float v0 = row[e.x];
    const float v1 = row[e.y];
    const float v2 = row[e.z];
    const float v3 = row[e.w];
    const float vb = row[0];
    float4 q;
    q.x = __expf(v0); q.y = __expf(v1); q.z = __expf(v2); q.w = __expf(v3);
    const float qb = __expf(vb);
    __syncthreads();   // vmcnt(0) drain: ALL loads (incl. row[0]) complete
                       // before any in-place store (WAR safety) — keep!
    *(float4*)(row + 4 * lane) = q;            // cols 4l..4l+3
    if (lane == 0) {
        const int t = r & (T_ - 1);
        blanks[(r & ~(T_ - 1)) + ((t + T_ - 1) & (T_ - 1))] = qb;  // shifted
    }
}

__global__ __launch_bounds__(128) void ctc_dp(
    const float* __restrict__ Q, const float* __restrict__ blanks,
    const int* __restrict__ labels, const int* __restrict__ input_lens,
    const int* __restrict__ label_lens, float* __restrict__ out)
{
    __shared__ float blk[T_];                  // shifted blank probs
    __shared__ float buf[NBUF][CH][256];       // staged label probs (64 KB)
    __shared__ int Pf, Cf;                     // produced / consumed counters
    const int b    = blockIdx.x;
    const int tid  = threadIdx.x;
    const int lane = tid & 63;
    const int wv   = tid >> 6;
    const float* Qb  = Q + (size_t)b * T_ * V_;
    const float* blg = blanks + b * T_;
    const int*  labb = labels + b * L_;
    const int il = input_lens[b];
    const int ll = label_lens[b];
    const int tend = il < T_ ? il : T_;

    if (tid == 0) { Pf = 0; Cf = 0; }
    __syncthreads();

    if (wv == 1) {
        // ---------------- producer ----------------
        #pragma unroll
        for (int i = 0; i < 4; ++i)
            __builtin_amdgcn_global_load_lds((gp_t)(blg + 256 * i + 4 * lane),
                                             (lp_t)&blk[256 * i], 16, 0, 0);
        #pragma unroll
        for (int i = 0; i < CH; ++i) {         // chunk 0 (rows t = 1..16)
            int t = 1 + i; if (t > T_ - 1) t = T_ - 1;
            __builtin_amdgcn_global_load_lds(
                (gp_t)(Qb + (size_t)t * V_ + 4 * lane),
                (lp_t)&buf[0][i][0], 16, 0, 0);
        }
        for (int c = 0; c < NCHUNK; ++c) {
            if (c + 1 < NCHUNK) {
                // ring slot (c+1)&3 must be free: consumer done with c+1-NBUF
                while (__hip_atomic_load(&Cf, __ATOMIC_ACQUIRE,
                                         __HIP_MEMORY_SCOPE_WORKGROUP) < c + 2 - NBUF) {}
                const int cb = (c + 1) & (NBUF - 1);
                #pragma unroll
                for (int i = 0; i < CH; ++i) {
                    int t = 1 + (c + 1) * CH + i; if (t > T_ - 1) t = T_ - 1;
                    __builtin_amdgcn_global_load_lds(
                        (gp_t)(Qb + (size_t)t * V_ + 4 * lane),
                        (lp_t)&buf[cb][i][0], 16, 0, 0);
                }
                // wait chunk c's 16 stages; chunk c+1's 16 stay in flight
                asm volatile("s_waitcnt vmcnt(16)" ::: "memory");
            } else {
                asm volatile("s_waitcnt vmcnt(0)" ::: "memory");
            }
            if (lane == 0)
                __hip_atomic_store(&Pf, c + 1, __ATOMIC_RELEASE,
                                   __HIP_MEMORY_SCOPE_WORKGROUP);
        }
    } else {
        // ---------------- consumer ----------------
        const int4 e  = *(const int4*)(labb + 4 * lane);
        const int  ep = (lane > 0) ? labb[4 * lane - 1] : -1;
        const float kf0 = ((8 * lane + 1) >= 3 && e.x != ep) ? 1.f : 0.f;
        const float kf1 = (e.y != e.x) ? 1.f : 0.f;
        const float kf2 = (e.z != e.y) ? 1.f : 0.f;
        const float kf3 = (e.w != e.z) ? 1.f : 0.f;
        const float bl0 = blg[T_ - 1];         // blank(t=0), shifted slot
        const float q00 = Qb[0];               // label-state-1 prob at t=0
        float p0 = (lane == 0) ? bl0 : 0.f;
        float p1 = (lane == 0) ? q00 : 0.f;
        float p2 = 0.f, p3 = 0.f, p4 = 0.f, p5 = 0.f,
              p6 = 0.f, p7 = 0.f, p8 = 0.f;
        int Esc = 0;        // true alpha = stored * 2^{-Esc}
        float pm1 = 0.f;    // alpha[8l-1] entering next step

        auto rescale = [&]() {
            float m = fmaxf(fmaxf(fmaxf(fmaxf(p0, p1), fmaxf(p2, p3)),
                                  fmaxf(fmaxf(p4, p5), fmaxf(p6, p7))), p8);
            #pragma unroll
            for (int off = 32; off >= 1; off >>= 1)
                m = fmaxf(m, __shfl_xor(m, off));
            const unsigned eb = (__float_as_uint(m) >> 23) & 0xffu;
            if (eb >= 1u && eb <= 253u) {
                const float sf = __uint_as_float((254u - eb) << 23); // exact 2^(127-eb)
                p0 *= sf; p1 *= sf; p2 *= sf; p3 *= sf; p4 *= sf;
                p5 *= sf; p6 *= sf; p7 *= sf; p8 *= sf; pm1 *= sf;
                Esc += 127 - (int)eb;
            }
        };

        for (int c = 0; c < NCHUNK; ++c) {
            while (__hip_atomic_load(&Pf, __ATOMIC_ACQUIRE,
                                     __HIP_MEMORY_SCOPE_WORKGROUP) <= c) {}
            const float* bufc = &buf[c & (NBUF - 1)][0][0];
            float4 bv;
            #pragma unroll
            for (int i = 0; i < CH; ++i) {
                if ((i & 3) == 0) bv = *(const float4*)&blk[c * CH + i]; // blk[t-1]
                const float qb = ((i & 3) == 0) ? bv.x : ((i & 3) == 1) ? bv.y
                               : ((i & 3) == 2) ? bv.z : bv.w;
                const int t = 1 + c * CH + i;
                if (t < tend) {                 // wave-uniform
                    const float4 q = *(const float4*)(bufc + i * 256 + 4 * lane);
                    const float n0 = (p0 + pm1) * qb;
                    const float n1 = fmaf(kf0, pm1, p1 + p0) * q.x;
                    const float n2 = (p2 + p1) * qb;
                    const float n3 = fmaf(kf1, p1, p3 + p2) * q.y;
                    const float n4 = (p4 + p3) * qb;
                    const float n5 = fmaf(kf2, p3, p5 + p4) * q.z;
                    const float n6 = (p6 + p5) * qb;
                    const float n7 = fmaf(kf3, p5, p7 + p6) * q.w;
                    const float n8 = (p8 + p7) * qb;   // state 8l+8 (512 @ lane63)
                    p0 = n0; p1 = n1; p2 = n2; p3 = n3; p4 = n4;
                    p5 = n5; p6 = n6; p7 = n7; p8 = n8;
                    pm1 = __shfl_up(p7, 1);
                    if (lane == 0) pm1 = 0.f;
                }
                if (i == 7) rescale();
            }
            rescale();
            if (lane == 0)
                __hip_atomic_store(&Cf, c + 1, __ATOMIC_RELEASE,
                                   __HIP_MEMORY_SCOPE_WORKGROUP);
        }

        // epilogue via shuffles only (no LDS, no barrier)
        const int sl = 2 * ll;                 // uniform
        auto pick = [&](int s) -> float {      // s uniform, 1..512
            if (s == 512) return __shfl(p8, 63);
            const int r = s & 7;
            float v = p0;
            v = (r == 1) ? p1 : v; v = (r == 2) ? p2 : v;
            v = (r == 3) ? p3 : v; v = (r == 4) ? p4 : v;
            v = (r == 5) ? p5 : v; v = (r == 6) ? p6 : v;
            v = (r == 7) ? p7 : v;
            return __shfl(v, s >> 3);
        };
        const float la = pick(sl);
        const float lb = pick(sl - 1);
        if (lane == 0) {
            const float tot = la + lb;
            float loss = (float)Esc * LN2F - __logf(tot);
            if (!(loss <= 1e29f)) loss = 0.f;  // zero_infinity
            atomicAdd(out, loss);
        }
    }
}

extern "C" void kernel_launch(void* const* d_in, const int* in_sizes, int n_in,
                              void* d_out, int out_size, void* d_ws, size_t ws_size,
                              hipStream_t stream) {
    float*       lp     = (float*)d_in[0];    // mutated by pass 1; restored each replay
    const int*   labels = (const int*)d_in[1];
    const int*   il     = (const int*)d_in[2];
    const int*   ll     = (const int*)d_in[3];
    float* out    = (float*)d_out;
    float* blanks = (float*)d_ws;             // B*T floats = 128 KB scratch

    hipMemsetAsync(out, 0, sizeof(float), stream);   // d_out re-poisoned each replay
    ctc_gather<<<dim3(B_ * T_ / 4), dim3(256), 0, stream>>>(lp, labels, blanks);
    ctc_dp<<<dim3(B_), dim3(128), 0, stream>>>(lp, blanks, labels, il, ll, out);
}

// Round 9
// 336.160 us; speedup vs baseline: 1.0190x; 1.0190x over previous
//
#include <hip/hip_runtime.h>

// CTC forward loss (sum, zero_infinity), B=32, T=1024, V=1024, L=256, S=513.
//
// Pass 1 (ctc_gather): per (b,t) row, gather the 257 needed probs, exp(),
//   write labels compacted in-place (cols 0..255); blank(t) stored at
//   blanks[b*T + (t-1 mod T)] so the DP reads blanks as aligned float4s.
//
// Pass 2 (ctc_dp): one block (2 waves) per batch item — producer/consumer
//   wave specialization (R6 skeleton: acquire/release LDS handshake, 4-deep
//   ring, global_load_lds(16B)). Consumer: depth-2 LDS read pipeline,
//   boundary-first shuffle, deferred pow-2 rescale (measured i=4/12, folded
//   into emissions at i=8 / next i=0 — exact pow2, off the critical path).
//
// NUMERICS (R8 post-mortem): rescale now targets max ~= 2^64, NOT [1,2).
//   Rescale-to-[1,2) put answer-relevant diagonal-band states (which run
//   tens of nats below the global state max mid-sequence, because the max
//   tracks states that can never reach s=512) within reach of the fp32
//   denormal flush floor. Targeting 2^64 moves the flush line from ~51-63
//   nats below the running max to ~107 nats. Scaling stays exact pow2;
//   overflow impossible (probs <= 1 => growth <= 3x/step, max <= ~2^77).

constexpr int B_ = 32, T_ = 1024, V_ = 1024, L_ = 256;
constexpr int S_ = 2 * L_ + 1;   // 513
constexpr int CH = 16;           // steps per chunk
constexpr int NCHUNK = 64;       // 64*16 covers t = 1..1024 (t>=tend guarded)
constexpr int NBUF = 4;          // LDS ring depth (64 KB)
constexpr float LN2F = 0.6931471805599453f;

typedef const __attribute__((address_space(1))) unsigned int* gp_t;
typedef __attribute__((address_space(3))) unsigned int* lp_t;

__global__ __launch_bounds__(256, 4) void ctc_gather(
    float* __restrict__ lp, const int* __restrict__ labels,
    float* __restrict__ blanks)
{
    const int wave = threadIdx.x >> 6;
    const int lane = threadIdx.x & 63;
    const int r = blockIdx.x * 4 + wave;       // row in [0, B*T)
    const int b = r >> 10;                     // T = 1024
    float* row = lp + (size_t)r * V_;
    const int* labb = labels + b * L_;

    const int4 e = *(const int4*)(labb + 4 * lane);
    const float v0 = row[e.x];
    const float v1 = row[e.y];
    const float v2 = row[e.z];
    const float v3 = row[e.w];
    const float vb = row[0];
    float4 q;
    q.x = __expf(v0); q.y = __expf(v1); q.z = __expf(v2); q.w = __expf(v3);
    const float qb = __expf(vb);
    __syncthreads();   // vmcnt(0) drain: ALL loads complete before any
                       // in-place store (WAR safety) — keep!
    *(float4*)(row + 4 * lane) = q;            // cols 4l..4l+3
    if (lane == 0) {
        const int t = r & (T_ - 1);
        blanks[(r & ~(T_ - 1)) + ((t + T_ - 1) & (T_ - 1))] = qb;  // shifted
    }
}

__global__ __launch_bounds__(128) void ctc_dp(
    const float* __restrict__ Q, const float* __restrict__ blanks,
    const int* __restrict__ labels, const int* __restrict__ input_lens,
    const int* __restrict__ label_lens, float* __restrict__ out)
{
    __shared__ float blk[T_];                  // shifted blank probs
    __shared__ float buf[NBUF][CH][256];       // staged label probs (64 KB)
    __shared__ int Pf, Cf;                     // produced / consumed counters
    const int b    = blockIdx.x;
    const int tid  = threadIdx.x;
    const int lane = tid & 63;
    const int wv   = tid >> 6;
    const float* Qb  = Q + (size_t)b * T_ * V_;
    const float* blg = blanks + b * T_;
    const int*  labb = labels + b * L_;
    const int il = input_lens[b];
    const int ll = label_lens[b];
    const int tend = il < T_ ? il : T_;

    if (tid == 0) { Pf = 0; Cf = 0; }
    __syncthreads();

    if (wv == 1) {
        // ---------------- producer (R6-proven) ----------------
        #pragma unroll
        for (int i = 0; i < 4; ++i)
            __builtin_amdgcn_global_load_lds((gp_t)(blg + 256 * i + 4 * lane),
                                             (lp_t)&blk[256 * i], 16, 0, 0);
        #pragma unroll
        for (int i = 0; i < CH; ++i) {         // chunk 0 (rows t = 1..16)
            int t = 1 + i; if (t > T_ - 1) t = T_ - 1;
            __builtin_amdgcn_global_load_lds(
                (gp_t)(Qb + (size_t)t * V_ + 4 * lane),
                (lp_t)&buf[0][i][0], 16, 0, 0);
        }
        for (int c = 0; c < NCHUNK; ++c) {
            if (c + 1 < NCHUNK) {
                while (__hip_atomic_load(&Cf, __ATOMIC_ACQUIRE,
                                         __HIP_MEMORY_SCOPE_WORKGROUP) < c + 2 - NBUF) {}
                const int cb = (c + 1) & (NBUF - 1);
                #pragma unroll
                for (int i = 0; i < CH; ++i) {
                    int t = 1 + (c + 1) * CH + i; if (t > T_ - 1) t = T_ - 1;
                    __builtin_amdgcn_global_load_lds(
                        (gp_t)(Qb + (size_t)t * V_ + 4 * lane),
                        (lp_t)&buf[cb][i][0], 16, 0, 0);
                }
                asm volatile("s_waitcnt vmcnt(16)" ::: "memory");
            } else {
                asm volatile("s_waitcnt vmcnt(0)" ::: "memory");
            }
            if (lane == 0)
                __hip_atomic_store(&Pf, c + 1, __ATOMIC_RELEASE,
                                   __HIP_MEMORY_SCOPE_WORKGROUP);
        }
    } else {
        // ---------------- consumer ----------------
        const int4 e  = *(const int4*)(labb + 4 * lane);
        const int  ep = (lane > 0) ? labb[4 * lane - 1] : -1;
        const float kf0 = ((8 * lane + 1) >= 3 && e.x != ep) ? 1.f : 0.f;
        const float kf1 = (e.y != e.x) ? 1.f : 0.f;
        const float kf2 = (e.z != e.y) ? 1.f : 0.f;
        const float kf3 = (e.w != e.z) ? 1.f : 0.f;
        const float bl0 = blg[T_ - 1];         // blank(t=0), shifted slot
        const float q00 = Qb[0];               // label-state-1 prob at t=0
        float p0 = (lane == 0) ? bl0 : 0.f;
        float p1 = (lane == 0) ? q00 : 0.f;
        float p2 = 0.f, p3 = 0.f, p4 = 0.f, p5 = 0.f,
              p6 = 0.f, p7 = 0.f, p8 = 0.f;
        int Esc = 0;        // true alpha = stored * 2^{-Esc}
        float pm1 = 0.f;    // alpha[8l-1] entering next step
        float sfP = 1.f, sfM = 1.f;            // pending deferred scales

        // Measure wave-max, return exact pow2 factor bringing it to ~2^64
        // (NOT [1,2): keeps answer-band states ~107 nats of flush headroom).
        auto snap = [&]() -> float {
            float m = fmaxf(fmaxf(fmaxf(fmaxf(p0, p1), fmaxf(p2, p3)),
                                  fmaxf(fmaxf(p4, p5), fmaxf(p6, p7))), p8);
            #pragma unroll
            for (int off = 32; off >= 1; off >>= 1)
                m = fmaxf(m, __shfl_xor(m, off));
            const unsigned eb = (__float_as_uint(m) >> 23) & 0xffu;
            if (eb >= 1u && eb <= 254u) {
                unsigned k = 318u - eb;        // biased exp of 2^(64-(eb-127))
                if (k > 254u) k = 254u;        // clamp (max sf = 2^127)
                Esc += (int)k - 127;
                return __uint_as_float(k << 23);   // exact 2^(k-127)
            }
            return 1.f;
        };

        for (int c = 0; c < NCHUNK; ++c) {
            while (__hip_atomic_load(&Pf, __ATOMIC_ACQUIRE,
                                     __HIP_MEMORY_SCOPE_WORKGROUP) <= c) {}
            const float* base = &buf[c & (NBUF - 1)][0][0] + 4 * lane;
            float4 qp0 = *(const float4*)(base);          // row i
            float4 qp1 = *(const float4*)(base + 256);    // row i+1
            float4 bv;
            #pragma unroll
            for (int i = 0; i < CH; ++i) {
                if ((i & 3) == 0) bv = *(const float4*)&blk[c * CH + i];
                float qb = ((i & 3) == 0) ? bv.x : ((i & 3) == 1) ? bv.y
                         : ((i & 3) == 2) ? bv.z : bv.w;
                float4 q = qp0;
                qp0 = qp1;                     // shift the 2-deep pipeline
                if (i < CH - 2)                // issue row i+2 (unguarded)
                    qp1 = *(const float4*)(base + (i + 2) * 256);
                if (i == 0) { q.x *= sfP; q.y *= sfP; q.z *= sfP; q.w *= sfP; qb *= sfP; }
                if (i == 8) { q.x *= sfM; q.y *= sfM; q.z *= sfM; q.w *= sfM; qb *= sfM; }
                const int t = 1 + c * CH + i;
                if (t < tend) {                // wave-uniform scalar branch
                    // boundary first: n7 feeds the shuffle; issue it early
                    const float n7 = fmaf(kf3, p5, p7 + p6) * q.w;
                    const float n8 = (p8 + p7) * qb;   // state 8l+8 (512@63)
                    float pm1n = __shfl_up(n7, 1);
                    if (lane == 0) pm1n = 0.f;
                    const float n0 = (p0 + pm1) * qb;
                    const float n1 = fmaf(kf0, pm1, p1 + p0) * q.x;
                    const float n2 = (p2 + p1) * qb;
                    const float n3 = fmaf(kf1, p1, p3 + p2) * q.y;
                    const float n4 = (p4 + p3) * qb;
                    const float n5 = fmaf(kf2, p3, p5 + p4) * q.z;
                    const float n6 = (p6 + p5) * qb;
                    p0 = n0; p1 = n1; p2 = n2; p3 = n3; p4 = n4;
                    p5 = n5; p6 = n6; p7 = n7; p8 = n8; pm1 = pm1n;
                }
                if (i == 4)  sfM = snap();     // applied at i==8
                if (i == 12) sfP = snap();     // applied at next chunk's i==0
            }
            if (lane == 0)
                __hip_atomic_store(&Cf, c + 1, __ATOMIC_RELEASE,
                                   __HIP_MEMORY_SCOPE_WORKGROUP);
        }
        // apply the last pending scale (its Esc contribution is counted)
        p0 *= sfP; p1 *= sfP; p2 *= sfP; p3 *= sfP; p4 *= sfP;
        p5 *= sfP; p6 *= sfP; p7 *= sfP; p8 *= sfP;

        // epilogue via shuffles only
        const int sl = 2 * ll;                 // uniform
        auto pick = [&](int s) -> float {      // s uniform, 1..512
            if (s == 512) return __shfl(p8, 63);
            const int r = s & 7;
            float v = p0;
            v = (r == 1) ? p1 : v; v = (r == 2) ? p2 : v;
            v = (r == 3) ? p3 : v; v = (r == 4) ? p4 : v;
            v = (r == 5) ? p5 : v; v = (r == 6) ? p6 : v;
            v = (r == 7) ? p7 : v;
            return __shfl(v, s >> 3);
        };
        const float la = pick(sl);
        const float lb = pick(sl - 1);
        if (lane == 0) {
            const float tot = la + lb;
            float loss = (float)Esc * LN2F - __logf(tot);
            if (!(loss <= 1e29f)) loss = 0.f;  // zero_infinity
            atomicAdd(out, loss);
        }
    }
}

extern "C" void kernel_launch(void* const* d_in, const int* in_sizes, int n_in,
                              void* d_out, int out_size, void* d_ws, size_t ws_size,
                              hipStream_t stream) {
    float*       lp     = (float*)d_in[0];    // mutated by pass 1; restored each replay
    const int*   labels = (const int*)d_in[1];
    const int*   il     = (const int*)d_in[2];
    const int*   ll     = (const int*)d_in[3];
    float* out    = (float*)d_out;
    float* blanks = (float*)d_ws;             // B*T floats = 128 KB scratch

    hipMemsetAsync(out, 0, sizeof(float), stream);   // d_out re-poisoned each replay
    ctc_gather<<<dim3(B_ * T_ / 4), dim3(256), 0, stream>>>(lp, labels, blanks);
    ctc_dp<<<dim3(B_), dim3(128), 0, stream>>>(lp, blanks, labels, il, ll, out);
}

// Round 10
// 300.465 us; speedup vs baseline: 1.1400x; 1.1188x over previous
//
#include <hip/hip_runtime.h>

// CTC forward loss (sum, zero_infinity), B=32, T=1024, V=1024, L=256, S=513.
//
// Pass 1 (ctc_gather): per (b,t) row, gather the 257 needed probs, exp(),
//   write labels compacted in-place (cols 0..255); blank(t) stored at
//   blanks[b*T + (t-1 mod T)] so the DP reads blanks as aligned float4s.
//
// Pass 2 (ctc_dp): one block (2 waves) per batch item — producer/consumer
//   wave specialization (R6/R9-proven producer, byte-identical).
//   Consumer (R9 post-mortem: 339 cyc/step was exposed LDS-pipe latency from
//   in-order dependent ds_permutes): all cross-lane traffic moved to DPP
//   (VALU pipe, ~2 cyc):
//     - snap() wave-max: row_shr:1/2/4/8 + row_bcast:15/31 DPP-fmax chain
//       + readlane(63)  (exact same max as the old 6x shfl_xor butterfly,
//       ~40 cyc instead of ~720);
//     - pm1 (alpha[8l-1]): wave_shr:1 DPP of n7 (lane0 zeroed by bound_ctrl)
//       instead of per-step ds_permute;
//     - blk float4 prefetched 3 steps early; q-rows depth-3 register pipe.
//   Numerics identical to R9 (pass, absmax 1024): linear domain, deferred
//   exact pow-2 rescale targeting max ~= 2^64 (flush headroom ~107 nats).

constexpr int B_ = 32, T_ = 1024, V_ = 1024, L_ = 256;
constexpr int S_ = 2 * L_ + 1;   // 513
constexpr int CH = 16;           // steps per chunk
constexpr int NCHUNK = 64;       // 64*16 covers t = 1..1024 (t>=tend guarded)
constexpr int NBUF = 4;          // LDS ring depth (64 KB)
constexpr float LN2F = 0.6931471805599453f;

typedef const __attribute__((address_space(1))) unsigned int* gp_t;
typedef __attribute__((address_space(3))) unsigned int* lp_t;

template <int CTRL>
__device__ __forceinline__ float dpp_fmax(float x) {
    // old=0, row_mask=bank_mask=0xf, bound_ctrl=1 (invalid src -> 0);
    // states are nonnegative so fmax with 0 is identity.
    const int t = __builtin_amdgcn_update_dpp(0, __float_as_int(x), CTRL, 0xf, 0xf, true);
    return fmaxf(x, __int_as_float(t));
}

__device__ __forceinline__ float wave_max_dpp(float x) {
    x = dpp_fmax<0x111>(x);   // row_shr:1
    x = dpp_fmax<0x112>(x);   // row_shr:2
    x = dpp_fmax<0x114>(x);   // row_shr:4
    x = dpp_fmax<0x118>(x);   // row_shr:8   (lane 15,31,47,63 = row max)
    x = dpp_fmax<0x142>(x);   // row_bcast:15
    x = dpp_fmax<0x143>(x);   // row_bcast:31 (lane 63 = wave max)
    return __int_as_float(__builtin_amdgcn_readlane(__float_as_int(x), 63));
}

__device__ __forceinline__ float dpp_wave_shr1(float x) {
    // lane i <- lane i-1 across the whole wave; lane 0 -> 0 (bound_ctrl)
    return __int_as_float(
        __builtin_amdgcn_update_dpp(0, __float_as_int(x), 0x138, 0xf, 0xf, true));
}

__global__ __launch_bounds__(256, 4) void ctc_gather(
    float* __restrict__ lp, const int* __restrict__ labels,
    float* __restrict__ blanks)
{
    const int wave = threadIdx.x >> 6;
    const int lane = threadIdx.x & 63;
    const int r = blockIdx.x * 4 + wave;       // row in [0, B*T)
    const int b = r >> 10;                     // T = 1024
    float* row = lp + (size_t)r * V_;
    const int* labb = labels + b * L_;

    const int4 e = *(const int4*)(labb + 4 * lane);
    const float v0 = row[e.x];
    const float v1 = row[e.y];
    const float v2 = row[e.z];
    const float v3 = row[e.w];
    const float vb = row[0];
    float4 q;
    q.x = __expf(v0); q.y = __expf(v1); q.z = __expf(v2); q.w = __expf(v3);
    const float qb = __expf(vb);
    __syncthreads();   // vmcnt(0) drain: ALL loads complete before any
                       // in-place store (WAR safety) — keep!
    *(float4*)(row + 4 * lane) = q;            // cols 4l..4l+3
    if (lane == 0) {
        const int t = r & (T_ - 1);
        blanks[(r & ~(T_ - 1)) + ((t + T_ - 1) & (T_ - 1))] = qb;  // shifted
    }
}

__global__ __launch_bounds__(128) void ctc_dp(
    const float* __restrict__ Q, const float* __restrict__ blanks,
    const int* __restrict__ labels, const int* __restrict__ input_lens,
    const int* __restrict__ label_lens, float* __restrict__ out)
{
    __shared__ float blk[T_ + 4];              // shifted blank probs (+pad for
                                               // the 3-step-early float4 read)
    __shared__ float buf[NBUF][CH][256];       // staged label probs (64 KB)
    __shared__ int Pf, Cf;                     // produced / consumed counters
    const int b    = blockIdx.x;
    const int tid  = threadIdx.x;
    const int lane = tid & 63;
    const int wv   = tid >> 6;
    const float* Qb  = Q + (size_t)b * T_ * V_;
    const float* blg = blanks + b * T_;
    const int*  labb = labels + b * L_;
    const int il = input_lens[b];
    const int ll = label_lens[b];
    const int tend = il < T_ ? il : T_;

    if (tid == 0) { Pf = 0; Cf = 0; }
    __syncthreads();

    if (wv == 1) {
        // ---------------- producer (R6/R9-proven, unchanged) --------------
        #pragma unroll
        for (int i = 0; i < 4; ++i)
            __builtin_amdgcn_global_load_lds((gp_t)(blg + 256 * i + 4 * lane),
                                             (lp_t)&blk[256 * i], 16, 0, 0);
        #pragma unroll
        for (int i = 0; i < CH; ++i) {         // chunk 0 (rows t = 1..16)
            int t = 1 + i; if (t > T_ - 1) t = T_ - 1;
            __builtin_amdgcn_global_load_lds(
                (gp_t)(Qb + (size_t)t * V_ + 4 * lane),
                (lp_t)&buf[0][i][0], 16, 0, 0);
        }
        for (int c = 0; c < NCHUNK; ++c) {
            if (c + 1 < NCHUNK) {
                while (__hip_atomic_load(&Cf, __ATOMIC_ACQUIRE,
                                         __HIP_MEMORY_SCOPE_WORKGROUP) < c + 2 - NBUF) {}
                const int cb = (c + 1) & (NBUF - 1);
                #pragma unroll
                for (int i = 0; i < CH; ++i) {
                    int t = 1 + (c + 1) * CH + i; if (t > T_ - 1) t = T_ - 1;
                    __builtin_amdgcn_global_load_lds(
                        (gp_t)(Qb + (size_t)t * V_ + 4 * lane),
                        (lp_t)&buf[cb][i][0], 16, 0, 0);
                }
                asm volatile("s_waitcnt vmcnt(16)" ::: "memory");
            } else {
                asm volatile("s_waitcnt vmcnt(0)" ::: "memory");
            }
            if (lane == 0)
                __hip_atomic_store(&Pf, c + 1, __ATOMIC_RELEASE,
                                   __HIP_MEMORY_SCOPE_WORKGROUP);
        }
    } else {
        // ---------------- consumer ----------------
        const int4 e  = *(const int4*)(labb + 4 * lane);
        const int  ep = (lane > 0) ? labb[4 * lane - 1] : -1;
        const float kf0 = ((8 * lane + 1) >= 3 && e.x != ep) ? 1.f : 0.f;
        const float kf1 = (e.y != e.x) ? 1.f : 0.f;
        const float kf2 = (e.z != e.y) ? 1.f : 0.f;
        const float kf3 = (e.w != e.z) ? 1.f : 0.f;
        const float bl0 = blg[T_ - 1];         // blank(t=0), shifted slot
        const float q00 = Qb[0];               // label-state-1 prob at t=0
        float p0 = (lane == 0) ? bl0 : 0.f;
        float p1 = (lane == 0) ? q00 : 0.f;
        float p2 = 0.f, p3 = 0.f, p4 = 0.f, p5 = 0.f,
              p6 = 0.f, p7 = 0.f, p8 = 0.f;
        int Esc = 0;        // true alpha = stored * 2^{-Esc}
        float pm1 = 0.f;    // alpha[8l-1] entering next step
        float sfP = 1.f, sfM = 1.f;            // pending deferred scales

        // Wave-max via DPP (VALU pipe, no LDS latency), exact pow2 factor
        // bringing it to ~2^64 (same numerics as R9 — identical max value).
        auto snap = [&]() -> float {
            float m = fmaxf(fmaxf(fmaxf(fmaxf(p0, p1), fmaxf(p2, p3)),
                                  fmaxf(fmaxf(p4, p5), fmaxf(p6, p7))), p8);
            m = wave_max_dpp(m);
            const unsigned eb = (__float_as_uint(m) >> 23) & 0xffu;
            if (eb >= 1u && eb <= 254u) {
                unsigned k = 318u - eb;        // biased exp of 2^(64-(eb-127))
                if (k > 254u) k = 254u;        // clamp (max sf = 2^127)
                Esc += (int)k - 127;
                return __uint_as_float(k << 23);   // exact 2^(k-127)
            }
            return 1.f;
        };

        for (int c = 0; c < NCHUNK; ++c) {
            while (__hip_atomic_load(&Pf, __ATOMIC_ACQUIRE,
                                     __HIP_MEMORY_SCOPE_WORKGROUP) <= c) {}
            const float* base = &buf[c & (NBUF - 1)][0][0] + 4 * lane;
            float4 qA = *(const float4*)(base);           // row i
            float4 qB = *(const float4*)(base + 256);     // row i+1
            float4 qC = *(const float4*)(base + 512);     // row i+2
            float4 bv = *(const float4*)&blk[c * CH];     // blanks, group 0
            float4 bvn;
            #pragma unroll
            for (int i = 0; i < CH; ++i) {
                const int g = i & 3;
                float qb = (g == 0) ? bv.x : (g == 1) ? bv.y
                         : (g == 2) ? bv.z : bv.w;
                float4 q = qA;
                qA = qB; qB = qC;                          // depth-3 pipe
                if (i < CH - 3)
                    qC = *(const float4*)(base + (i + 3) * 256);
                if (g == 1) bvn = *(const float4*)&blk[c * CH + i + 3];
                if (g == 3) bv = bvn;
                if (i == 0) { q.x *= sfP; q.y *= sfP; q.z *= sfP; q.w *= sfP; qb *= sfP; }
                if (i == 8) { q.x *= sfM; q.y *= sfM; q.z *= sfM; q.w *= sfM; qb *= sfM; }
                const int t = 1 + c * CH + i;
                if (t < tend) {                // wave-uniform scalar branch
                    // boundary first; pm1 for next step via DPP (VALU pipe)
                    const float n7 = fmaf(kf3, p5, p7 + p6) * q.w;
                    const float n8 = (p8 + p7) * qb;   // state 8l+8 (512@63)
                    const float pm1n = dpp_wave_shr1(n7);  // lane0 -> 0
                    const float n0 = (p0 + pm1) * qb;
                    const float n1 = fmaf(kf0, pm1, p1 + p0) * q.x;
                    const float n2 = (p2 + p1) * qb;
                    const float n3 = fmaf(kf1, p1, p3 + p2) * q.y;
                    const float n4 = (p4 + p3) * qb;
                    const float n5 = fmaf(kf2, p3, p5 + p4) * q.z;
                    const float n6 = (p6 + p5) * qb;
                    p0 = n0; p1 = n1; p2 = n2; p3 = n3; p4 = n4;
                    p5 = n5; p6 = n6; p7 = n7; p8 = n8; pm1 = pm1n;
                }
                if (i == 4)  sfM = snap();     // applied at i==8
                if (i == 12) sfP = snap();     // applied at next chunk's i==0
            }
            if (lane == 0)
                __hip_atomic_store(&Cf, c + 1, __ATOMIC_RELEASE,
                                   __HIP_MEMORY_SCOPE_WORKGROUP);
        }
        // apply the last pending scale (its Esc contribution is counted)
        p0 *= sfP; p1 *= sfP; p2 *= sfP; p3 *= sfP; p4 *= sfP;
        p5 *= sfP; p6 *= sfP; p7 *= sfP; p8 *= sfP;

        // epilogue via shuffles only (once — latency irrelevant)
        const int sl = 2 * ll;                 // uniform
        auto pick = [&](int s) -> float {      // s uniform, 1..512
            if (s == 512) return __shfl(p8, 63);
            const int r = s & 7;
            float v = p0;
            v = (r == 1) ? p1 : v; v = (r == 2) ? p2 : v;
            v = (r == 3) ? p3 : v; v = (r == 4) ? p4 : v;
            v = (r == 5) ? p5 : v; v = (r == 6) ? p6 : v;
            v = (r == 7) ? p7 : v;
            return __shfl(v, s >> 3);
        };
        const float la = pick(sl);
        const float lb = pick(sl - 1);
        if (lane == 0) {
            const float tot = la + lb;
            float loss = (float)Esc * LN2F - __logf(tot);
            if (!(loss <= 1e29f)) loss = 0.f;  // zero_infinity
            atomicAdd(out, loss);
        }
    }
}

extern "C" void kernel_launch(void* const* d_in, const int* in_sizes, int n_in,
                              void* d_out, int out_size, void* d_ws, size_t ws_size,
                              hipStream_t stream) {
    float*       lp     = (float*)d_in[0];    // mutated by pass 1; restored each replay
    const int*   labels = (const int*)d_in[1];
    const int*   il     = (const int*)d_in[2];
    const int*   ll     = (const int*)d_in[3];
    float* out    = (float*)d_out;
    float* blanks = (float*)d_ws;             // B*T floats = 128 KB scratch

    hipMemsetAsync(out, 0, sizeof(float), stream);   // d_out re-poisoned each replay
    ctc_gather<<<dim3(B_ * T_ / 4), dim3(256), 0, stream>>>(lp, labels, blanks);
    ctc_dp<<<dim3(B_), dim3(128), 0, stream>>>(lp, blanks, labels, il, ll, out);
}